// Round 2
// baseline (241.740 us; speedup 1.0000x reference)
//
#include <hip/hip_runtime.h>
#include <hip/hip_fp16.h>

// GAT: N=4096 nodes, F=512 in-feats, H=8 heads, D=64 head-dim.
//
// Key identity: score(h,i,j) = leaky(es_i + en_j), leaky piecewise-linear =>
//   exp(score - M_i) = (es_i+en_j>=0) ? exp(es_i-M_i)*exp(en_j)
//                                     : exp(0.2*es_i-M_i)*exp(0.2*en_j)
// with M_i = leaky(es_i + max_j en_j) a guaranteed upper bound (no online max,
// no rescale, j-partials combine additively). Mask = multiply by A (0/1).
//
// Pipeline:
//  prep:   cast X->f16, transpose W -> WT[h][d][f] f16
//  feats:  featsT[h][d][n] via mfma_16x16x32_f16; epilogue writes e_self,
//          e_neigh, u=exp(en), v=exp(0.2*en)
//  enmax:  per-head max of e_neigh
//  attn:   no-softmax-state flash; block = 16 rows x 8 heads x 2 j-halves
//          (16 waves, no barriers in loop, A served by L1 across heads)

#define NODES 4096
#define FEAT  512
#define HEADS 8
#define DH    64

using half8 = __attribute__((ext_vector_type(8))) _Float16;
using f32x4 = __attribute__((ext_vector_type(4))) float;
using f32x2 = __attribute__((ext_vector_type(2))) float;

// ---------------- prep ----------------
__global__ void prep_kernel(const float* __restrict__ X, const float* __restrict__ W,
                            _Float16* __restrict__ Xh, _Float16* __restrict__ WT) {
    int idx = blockIdx.x * blockDim.x + threadIdx.x;
    const int nx = NODES * FEAT;
    if (idx < nx) {
        Xh[idx] = (_Float16)X[idx];
    } else {
        int t = idx - nx;
        if (t < HEADS * DH * FEAT) {
            int h   = t / (DH * FEAT);
            int rem = t - h * (DH * FEAT);
            int d   = rem / FEAT;
            int f   = rem - d * FEAT;
            WT[t] = (_Float16)W[(h * FEAT + f) * DH + d];
        }
    }
}

// ---------------- feats ----------------
__global__ __launch_bounds__(256) void feats_kernel(
    const _Float16* __restrict__ Xh, const _Float16* __restrict__ WT,
    const float* __restrict__ a_self, const float* __restrict__ a_neigh,
    _Float16* __restrict__ featsT, float* __restrict__ e_self, float* __restrict__ e_neigh,
    float* __restrict__ u_tab, float* __restrict__ v_tab) {
    const int h    = blockIdx.y;
    const int tid  = threadIdx.x;
    const int w    = tid >> 6;
    const int lane = tid & 63;
    const int l15  = lane & 15;
    const int g    = lane >> 4;
    const int n0   = blockIdx.x * 64 + w * 16;

    f32x4 acc[4] = {};
    const _Float16* xb = Xh + (n0 + l15) * FEAT + g * 8;
    const _Float16* wb = WT + (h * DH + l15) * FEAT + g * 8;

#pragma unroll
    for (int kk = 0; kk < FEAT / 32; ++kk) {
        half8 b = *(const half8*)(xb + kk * 32);
#pragma unroll
        for (int mi = 0; mi < 4; ++mi) {
            half8 a = *(const half8*)(wb + mi * 16 * FEAT + kk * 32);
            acc[mi] = __builtin_amdgcn_mfma_f32_16x16x32_f16(a, b, acc[mi], 0, 0, 0);
        }
    }

    float ps = 0.f, pn = 0.f;
#pragma unroll
    for (int mi = 0; mi < 4; ++mi) {
#pragma unroll
        for (int r = 0; r < 4; ++r) {
            int d = mi * 16 + g * 4 + r;
            float v = acc[mi][r];
            featsT[(h * DH + d) * NODES + n0 + l15] = (_Float16)v;
            ps += v * a_self[h * DH + d];
            pn += v * a_neigh[h * DH + d];
        }
    }
    ps += __shfl_xor(ps, 16); ps += __shfl_xor(ps, 32);
    pn += __shfl_xor(pn, 16); pn += __shfl_xor(pn, 32);
    if (g == 0) {
        int n = n0 + l15;
        e_self[h * NODES + n]  = ps;
        e_neigh[h * NODES + n] = pn;
        u_tab[h * NODES + n]   = __expf(pn);
        v_tab[h * NODES + n]   = __expf(0.2f * pn);
    }
}

// ---------------- enmax: per-head max of e_neigh ----------------
__global__ __launch_bounds__(512) void enmax_kernel(const float* __restrict__ en,
                                                    float* __restrict__ enmax) {
    const int h = threadIdx.x >> 6, lane = threadIdx.x & 63;
    float m = -INFINITY;
    for (int k = lane; k < NODES; k += 64) m = fmaxf(m, en[h * NODES + k]);
#pragma unroll
    for (int s = 32; s; s >>= 1) m = fmaxf(m, __shfl_xor(m, s));
    if (lane == 0) enmax[h] = m;
}

// ---------------- attn ----------------
// grid N/16 = 256 blocks, 1024 threads = 16 waves. wave w: head = w&7,
// j-half = w>>3 (cols half*2048 .. +2048). No barrier in the main loop;
// halves combine additively via LDS at the end (fixed subtractor M_i).
__global__ __launch_bounds__(1024) void attn_kernel(
    const float* __restrict__ A, const _Float16* __restrict__ featsT,
    const float* __restrict__ e_self, const float* __restrict__ u_tab,
    const float* __restrict__ v_tab, const float* __restrict__ enmax,
    const float* __restrict__ bias, float* __restrict__ out) {
    __shared__ float cacc[HEADS][16][65];
    __shared__ float csum[HEADS][16];

    const int tid  = threadIdx.x;
    const int w    = tid >> 6;
    const int h    = w & 7;
    const int half = w >> 3;
    const int lane = tid & 63;
    const int l15  = lane & 15;
    const int g    = lane >> 4;
    const int i0   = blockIdx.x * 16;

    // per-row constants (row = l15, duplicated across g)
    const float es  = e_self[h * NODES + i0 + l15];
    const float em  = enmax[h];
    const float t0  = es + em;
    const float M   = fmaxf(t0, 0.2f * t0);
    const float c1  = __expf(es - M);
    const float c2  = __expf(0.2f * es - M);
    const float thr = __expf(-es);   // u_j >= thr  <=>  es + en_j >= 0

    const float* Ar = A + (size_t)(i0 + l15) * NODES + g * 8;
    const float* ub = u_tab + h * NODES + g * 8;
    const float* vb = v_tab + h * NODES + g * 8;
    const _Float16* fb = featsT + (size_t)(h * DH) * NODES + g * 8;

    f32x4 acc[4] = {};
    f32x4 ps4 = {};

    const int jt0 = half * (NODES / 128);
    const int jt1 = jt0 + NODES / 128;
    for (int jt = jt0; jt < jt1; ++jt) {
        const int j0 = jt * 64;
        half8 pa[2];
#pragma unroll
        for (int kk = 0; kk < 2; ++kk) {
            const int off = j0 + kk * 32;
            const f32x4 a0 = *(const f32x4*)(Ar + off);
            const f32x4 a1 = *(const f32x4*)(Ar + off + 4);
            const f32x4 u0 = *(const f32x4*)(ub + off);
            const f32x4 u1 = *(const f32x4*)(ub + off + 4);
            const f32x4 v0 = *(const f32x4*)(vb + off);
            const f32x4 v1 = *(const f32x4*)(vb + off + 4);
#pragma unroll
            for (int e = 0; e < 4; ++e) {
                float p0 = ((u0[e] >= thr) ? c1 * u0[e] : c2 * v0[e]) * a0[e];
                float p1 = ((u1[e] >= thr) ? c1 * u1[e] : c2 * v1[e]) * a1[e];
                ps4[e] += p0 + p1;
                pa[kk][e]     = (_Float16)p0;
                pa[kk][e + 4] = (_Float16)p1;
            }
        }
#pragma unroll
        for (int ni = 0; ni < 4; ++ni) {
            const _Float16* vp = fb + (size_t)(ni * 16 + l15) * NODES + j0;
            acc[ni] = __builtin_amdgcn_mfma_f32_16x16x32_f16(pa[0], *(const half8*)(vp), acc[ni], 0, 0, 0);
            acc[ni] = __builtin_amdgcn_mfma_f32_16x16x32_f16(pa[1], *(const half8*)(vp + 32), acc[ni], 0, 0, 0);
        }
    }

    // row sum (row = l15) for this j-half
    float ps = ps4[0] + ps4[1] + ps4[2] + ps4[3];
    ps += __shfl_xor(ps, 16);
    ps += __shfl_xor(ps, 32);

    if (half == 1) {
#pragma unroll
        for (int ni = 0; ni < 4; ++ni)
#pragma unroll
            for (int r = 0; r < 4; ++r)
                cacc[h][g * 4 + r][ni * 16 + l15] = acc[ni][r];
        if (g == 0) csum[h][l15] = ps;
    }
    __syncthreads();
    if (half == 0) {
        float inv[4];
#pragma unroll
        for (int r = 0; r < 4; ++r) {
            int row = g * 4 + r;
            float s0 = __shfl(ps, row);       // lane 'row' holds row-sum for l15==row
            inv[r] = 1.0f / (s0 + csum[h][row]);
        }
#pragma unroll
        for (int ni = 0; ni < 4; ++ni) {
            int d = ni * 16 + l15;
            float bb = bias[h * DH + d];
#pragma unroll
            for (int r = 0; r < 4; ++r) {
                float v = (acc[ni][r] + cacc[h][g * 4 + r][d]) * inv[r] + bb;
                out[(size_t)(i0 + g * 4 + r) * (HEADS * DH) + h * DH + d] = fmaxf(v, 0.f);
            }
        }
    }
}

extern "C" void kernel_launch(void* const* d_in, const int* in_sizes, int n_in,
                              void* d_out, int out_size, void* d_ws, size_t ws_size,
                              hipStream_t stream) {
    const float* X       = (const float*)d_in[0];
    const float* A       = (const float*)d_in[1];
    const float* W       = (const float*)d_in[2];
    const float* b       = (const float*)d_in[3];
    const float* a_self  = (const float*)d_in[4];
    const float* a_neigh = (const float*)d_in[5];
    float* out = (float*)d_out;

    char* ws = (char*)d_ws;
    size_t off = 0;
    _Float16* Xh     = (_Float16*)(ws + off); off += (size_t)NODES * FEAT * 2;       // 4 MB
    _Float16* WT     = (_Float16*)(ws + off); off += (size_t)HEADS * DH * FEAT * 2;  // 512 KB
    _Float16* featsT = (_Float16*)(ws + off); off += (size_t)HEADS * DH * NODES * 2; // 4 MB
    float* e_self    = (float*)(ws + off);    off += (size_t)HEADS * NODES * 4;
    float* e_neigh   = (float*)(ws + off);    off += (size_t)HEADS * NODES * 4;
    float* u_tab     = (float*)(ws + off);    off += (size_t)HEADS * NODES * 4;
    float* v_tab     = (float*)(ws + off);    off += (size_t)HEADS * NODES * 4;
    float* enmax     = (float*)(ws + off);    off += 64;

    const int total = NODES * FEAT + HEADS * DH * FEAT;
    prep_kernel<<<(total + 255) / 256, 256, 0, stream>>>(X, W, Xh, WT);
    feats_kernel<<<dim3(NODES / 64, HEADS), 256, 0, stream>>>(
        Xh, WT, a_self, a_neigh, featsT, e_self, e_neigh, u_tab, v_tab);
    enmax_kernel<<<1, 512, 0, stream>>>(e_neigh, enmax);
    attn_kernel<<<NODES / 16, 1024, 0, stream>>>(
        A, featsT, e_self, u_tab, v_tab, enmax, b, out);
}

// Round 3
// 111.071 us; speedup vs baseline: 2.1764x; 2.1764x over previous
//
#include <hip/hip_runtime.h>
#include <hip/hip_fp16.h>
#include <stdint.h>

// GAT: N=4096, F=512, H=8, D=64.
// score(h,i,j) = leaky(es_i + en_j); exp(leaky-M) = max(c1*u, c2*v) with
//   u=exp(en), v=exp(0.2*en), c1=exp(es-M), c2=exp(0.2*es-M)  (max picks the
//   correct linear piece of leaky); mask = multiply by A (0/1); fixed M per row
//   => no online softmax state, partials combine additively across j-splits.

#define NODES 4096
#define FEAT  512
#define HEADS 8
#define DH    64
#define NT    (NODES / 64)           // 64 j-tiles
#define JSPLIT 4
#define BM 64
#define BK 64
#define JRANGE (NODES / JSPLIT)      // 1024
#define STEPS (JRANGE / BK)          // 16

using half2v = __attribute__((ext_vector_type(2))) _Float16;
using half4v = __attribute__((ext_vector_type(4))) _Float16;
using half8  = __attribute__((ext_vector_type(8))) _Float16;
using f32x4  = __attribute__((ext_vector_type(4))) float;

__device__ __forceinline__ void gll16(const void* g, void* l) {
    __builtin_amdgcn_global_load_lds(
        (const __attribute__((address_space(1))) uint32_t*)g,
        (__attribute__((address_space(3))) uint32_t*)l, 16, 0, 0);
}

// ---------------- prep: X->f16, W[h][f][d] -> WT[h][d][f] f16 ----------------
__global__ void prep_kernel(const float* __restrict__ X, const float* __restrict__ W,
                            _Float16* __restrict__ Xh, _Float16* __restrict__ WT) {
    int idx = blockIdx.x * blockDim.x + threadIdx.x;
    const int nx = NODES * FEAT;
    if (idx < nx) {
        Xh[idx] = (_Float16)X[idx];
    } else {
        int t = idx - nx;
        if (t < HEADS * DH * FEAT) {
            int h   = t / (DH * FEAT);
            int rem = t - h * (DH * FEAT);
            int d   = rem / FEAT;
            int f   = rem - d * FEAT;
            WT[t] = (_Float16)W[(h * FEAT + f) * DH + d];
        }
    }
}

// ---------------- feats: Vt tiled [h][jt][d][jj] f16 + e/u/v tables ----------------
__global__ __launch_bounds__(256) void feats_kernel(
    const _Float16* __restrict__ Xh, const _Float16* __restrict__ WT,
    const float* __restrict__ a_self, const float* __restrict__ a_neigh,
    _Float16* __restrict__ Vt, float* __restrict__ e_self, float* __restrict__ e_neigh,
    _Float16* __restrict__ u_tab, _Float16* __restrict__ v_tab) {
    const int h    = blockIdx.y;
    const int tid  = threadIdx.x;
    const int w    = tid >> 6;
    const int lane = tid & 63;
    const int l15  = lane & 15;
    const int g    = lane >> 4;
    const int bx   = blockIdx.x;
    const int n0   = bx * 64 + w * 16;

    f32x4 acc[4] = {};
    const _Float16* xb = Xh + (n0 + l15) * FEAT + g * 8;
    const _Float16* wb = WT + (h * DH + l15) * FEAT + g * 8;

#pragma unroll
    for (int kk = 0; kk < FEAT / 32; ++kk) {
        half8 b = *(const half8*)(xb + kk * 32);
#pragma unroll
        for (int mi = 0; mi < 4; ++mi) {
            half8 a = *(const half8*)(wb + mi * 16 * FEAT + kk * 32);
            acc[mi] = __builtin_amdgcn_mfma_f32_16x16x32_f16(a, b, acc[mi], 0, 0, 0);
        }
    }

    float ps = 0.f, pn = 0.f;
#pragma unroll
    for (int mi = 0; mi < 4; ++mi) {
#pragma unroll
        for (int r = 0; r < 4; ++r) {
            int d = mi * 16 + g * 4 + r;
            float v = acc[mi][r];
            Vt[((size_t)h * NT + bx) * 4096 + d * 64 + w * 16 + l15] = (_Float16)v;
            ps += v * a_self[h * DH + d];
            pn += v * a_neigh[h * DH + d];
        }
    }
    ps += __shfl_xor(ps, 16); ps += __shfl_xor(ps, 32);
    pn += __shfl_xor(pn, 16); pn += __shfl_xor(pn, 32);
    if (g == 0) {
        int n = n0 + l15;
        e_self[h * NODES + n]  = ps;
        e_neigh[h * NODES + n] = pn;
        u_tab[h * NODES + n]   = (_Float16)__expf(pn);
        v_tab[h * NODES + n]   = (_Float16)__expf(0.2f * pn);
    }
}

// ---------------- enmax: per-head max of e_neigh ----------------
__global__ __launch_bounds__(512) void enmax_kernel(const float* __restrict__ en,
                                                    float* __restrict__ enmax) {
    const int h = threadIdx.x >> 6, lane = threadIdx.x & 63;
    float m = -INFINITY;
    for (int k = lane; k < NODES; k += 64) m = fmaxf(m, en[h * NODES + k]);
#pragma unroll
    for (int s = 32; s; s >>= 1) m = fmaxf(m, __shfl_xor(m, s));
    if (lane == 0) enmax[h] = m;
}

// ---------------- attn: grid 256 = (64 i-tiles x 4 j-splits), 16 waves ----------------
// wave w: head h=w&7, rowhalf rh=w>>3 (32 rows). Per step: stage A(64x64 f32->f16,
// reg path) + V(8h x 64d x 64j f16, global_load_lds from tiled layout), both
// XOR-swizzled in LDS; packed-f16 p = max(c1*u, c2*v)*a; PV + ones-MFMA rowsum.
__global__ __launch_bounds__(1024) void attn_kernel(
    const float* __restrict__ A, const _Float16* __restrict__ Vt,
    const float* __restrict__ e_self, const _Float16* __restrict__ u_tab,
    const _Float16* __restrict__ v_tab, const float* __restrict__ enmax,
    float* __restrict__ out_acc, float* __restrict__ psum) {
    __shared__ _Float16 Vlds[2][HEADS * 64 * 64];   // 2 x 64KB
    __shared__ _Float16 Alds[2][64 * 64];           // 2 x 8KB

    const int tid  = threadIdx.x;
    const int w    = tid >> 6;
    const int lane = tid & 63;
    const int l15  = lane & 15;
    const int g    = lane >> 4;
    const int h    = w & 7;
    const int rh   = w >> 3;
    const int bx   = blockIdx.x;
    const int it   = bx >> 2;
    const int jp   = bx & 3;
    const int i0   = it * BM;
    const int jbase = jp * JRANGE;

    // per-lane row constants (rows rh*32 + mi*16 + l15)
    half2v c1h[2], c2h[2];
    const float em = enmax[h];
#pragma unroll
    for (int mi = 0; mi < 2; ++mi) {
        float es = e_self[h * NODES + i0 + rh * 32 + mi * 16 + l15];
        float t  = es + em;
        float M  = fmaxf(t, 0.2f * t);
        _Float16 c1 = (_Float16)__expf(es - M);
        _Float16 c2 = (_Float16)__expf(0.2f * es - M);
        c1h[mi] = half2v{c1, c1};
        c2h[mi] = half2v{c2, c2};
    }

    // staging geometry
    const int ar  = tid >> 4;   // A row 0..63
    const int acg = tid & 15;   // 16B f32 col-group

    f32x4 acc[2][4] = {};
    f32x4 asum[2]   = {};
    half8 ones;
#pragma unroll
    for (int e = 0; e < 8; ++e) ones[e] = (_Float16)1.0f;

    // ---- stage step 0 ----
    {
        const int jt = jp * STEPS;
#pragma unroll
        for (int p = 0; p < 4; ++p) {
            int ro = (p * 16 + w) * 1024 + lane * 16;   // byte offset in V region
            int hh = ro >> 13;
            int d  = (ro >> 7) & 63;
            int cs = ((ro >> 4) & 7) ^ (d & 7);
            const _Float16* src = Vt + ((size_t)(hh * NT + jt) * 4096 + d * 64 + cs * 8);
            gll16(src, (char*)&Vlds[0][0] + (p * 16 + w) * 1024);
        }
        f32x4 a0 = *(const f32x4*)(A + (size_t)(i0 + ar) * NODES + jbase + acg * 4);
        int c = acg >> 1, hs = acg & 1;
        _Float16* dst = &Alds[0][0] + ar * 64 + ((c ^ (ar & 7)) * 8) + hs * 4;
        *(half4v*)dst = half4v{(_Float16)a0[0], (_Float16)a0[1], (_Float16)a0[2], (_Float16)a0[3]};
    }
    __syncthreads();

    for (int s = 0; s < STEPS; ++s) {
        const int cur = s & 1, nxt = cur ^ 1;
        f32x4 an = {};
        if (s + 1 < STEPS) {
            const int jt = jp * STEPS + s + 1;
#pragma unroll
            for (int p = 0; p < 4; ++p) {
                int ro = (p * 16 + w) * 1024 + lane * 16;
                int hh = ro >> 13;
                int d  = (ro >> 7) & 63;
                int cs = ((ro >> 4) & 7) ^ (d & 7);
                const _Float16* src = Vt + ((size_t)(hh * NT + jt) * 4096 + d * 64 + cs * 8);
                gll16(src, (char*)&Vlds[nxt][0] + (p * 16 + w) * 1024);
            }
            an = *(const f32x4*)(A + (size_t)(i0 + ar) * NODES + jbase + (s + 1) * BK + acg * 4);
        }

        const int j0 = jbase + s * BK;
        half8 paf[2][2];
#pragma unroll
        for (int kk = 0; kk < 2; ++kk) {
            half8 uf = *(const half8*)(u_tab + h * NODES + j0 + kk * 32 + g * 8);
            half8 vf = *(const half8*)(v_tab + h * NODES + j0 + kk * 32 + g * 8);
#pragma unroll
            for (int mi = 0; mi < 2; ++mi) {
                const int row = rh * 32 + mi * 16 + l15;
                const half8 af = *(const half8*)(&Alds[cur][row * 64 + (((kk * 4 + g) ^ (row & 7)) * 8)]);
#pragma unroll
                for (int q = 0; q < 4; ++q) {
                    half2v u2 = half2v{uf[2 * q], uf[2 * q + 1]};
                    half2v v2 = half2v{vf[2 * q], vf[2 * q + 1]};
                    half2v a2 = half2v{af[2 * q], af[2 * q + 1]};
                    half2v p2 = __builtin_elementwise_max(u2 * c1h[mi], v2 * c2h[mi]) * a2;
                    paf[mi][kk][2 * q]     = p2[0];
                    paf[mi][kk][2 * q + 1] = p2[1];
                }
            }
        }
#pragma unroll
        for (int ni = 0; ni < 4; ++ni) {
            const int d = ni * 16 + l15;
#pragma unroll
            for (int kk = 0; kk < 2; ++kk) {
                const half8 vfr = *(const half8*)(&Vlds[cur][h * 4096 + d * 64 + (((kk * 4 + g) ^ (d & 7)) * 8)]);
                acc[0][ni] = __builtin_amdgcn_mfma_f32_16x16x32_f16(paf[0][kk], vfr, acc[0][ni], 0, 0, 0);
                acc[1][ni] = __builtin_amdgcn_mfma_f32_16x16x32_f16(paf[1][kk], vfr, acc[1][ni], 0, 0, 0);
            }
        }
#pragma unroll
        for (int mi = 0; mi < 2; ++mi) {
            asum[mi] = __builtin_amdgcn_mfma_f32_16x16x32_f16(paf[mi][0], ones, asum[mi], 0, 0, 0);
            asum[mi] = __builtin_amdgcn_mfma_f32_16x16x32_f16(paf[mi][1], ones, asum[mi], 0, 0, 0);
        }

        if (s + 1 < STEPS) {
            int c = acg >> 1, hs = acg & 1;
            _Float16* dst = &Alds[nxt][0] + ar * 64 + ((c ^ (ar & 7)) * 8) + hs * 4;
            *(half4v*)dst = half4v{(_Float16)an[0], (_Float16)an[1], (_Float16)an[2], (_Float16)an[3]};
        }
        __syncthreads();
    }

    // ---- epilogue: atomic partials (D-frag: row = g*4+r+16mi+32rh, col = l15) ----
    if (l15 == 0) {
#pragma unroll
        for (int mi = 0; mi < 2; ++mi)
#pragma unroll
            for (int r = 0; r < 4; ++r)
                atomicAdd(&psum[h * NODES + i0 + rh * 32 + mi * 16 + g * 4 + r], asum[mi][r]);
    }
#pragma unroll
    for (int mi = 0; mi < 2; ++mi)
#pragma unroll
        for (int ni = 0; ni < 4; ++ni)
#pragma unroll
            for (int r = 0; r < 4; ++r) {
                int row = i0 + rh * 32 + mi * 16 + g * 4 + r;
                atomicAdd(&out_acc[(size_t)row * 512 + h * 64 + ni * 16 + l15], acc[mi][ni][r]);
            }
}

// ---------------- finalize: out = relu(acc/psum + b) ----------------
__global__ __launch_bounds__(256) void finalize_kernel(
    const float* __restrict__ acc, const float* __restrict__ psum,
    const float* __restrict__ bias, float* __restrict__ out) {
    int i = blockIdx.x * 256 + threadIdx.x;
    int base = i * 4;
    int row = base >> 9, hd = base & 511, h = hd >> 6;
    f32x4 a = *(const f32x4*)(acc + base);
    f32x4 b = *(const f32x4*)(bias + hd);
    float inv = 1.0f / psum[h * NODES + row];
    f32x4 o;
#pragma unroll
    for (int e = 0; e < 4; ++e) o[e] = fmaxf(a[e] * inv + b[e], 0.f);
    *(f32x4*)(out + base) = o;
}

extern "C" void kernel_launch(void* const* d_in, const int* in_sizes, int n_in,
                              void* d_out, int out_size, void* d_ws, size_t ws_size,
                              hipStream_t stream) {
    const float* X       = (const float*)d_in[0];
    const float* A       = (const float*)d_in[1];
    const float* W       = (const float*)d_in[2];
    const float* b       = (const float*)d_in[3];
    const float* a_self  = (const float*)d_in[4];
    const float* a_neigh = (const float*)d_in[5];
    float* out = (float*)d_out;

    char* ws = (char*)d_ws;
    size_t off = 0;
    float* out_acc   = (float*)(ws + off);     off += (size_t)NODES * 512 * 4;        // 8 MB
    float* psum      = (float*)(ws + off);     off += (size_t)HEADS * NODES * 4;      // 128 KB
    size_t zbytes = off;
    _Float16* Xh     = (_Float16*)(ws + off);  off += (size_t)NODES * FEAT * 2;       // 4 MB
    _Float16* WT     = (_Float16*)(ws + off);  off += (size_t)HEADS * DH * FEAT * 2;  // 512 KB
    _Float16* Vt     = (_Float16*)(ws + off);  off += (size_t)HEADS * DH * NODES * 2; // 4 MB
    float* e_self    = (float*)(ws + off);     off += (size_t)HEADS * NODES * 4;
    float* e_neigh   = (float*)(ws + off);     off += (size_t)HEADS * NODES * 4;
    _Float16* u_tab  = (_Float16*)(ws + off);  off += (size_t)HEADS * NODES * 2;
    _Float16* v_tab  = (_Float16*)(ws + off);  off += (size_t)HEADS * NODES * 2;
    float* enmax     = (float*)(ws + off);     off += 64;

    hipMemsetAsync(out_acc, 0, zbytes, stream);

    const int total = NODES * FEAT + HEADS * DH * FEAT;
    prep_kernel<<<(total + 255) / 256, 256, 0, stream>>>(X, W, Xh, WT);
    feats_kernel<<<dim3(NODES / 64, HEADS), 256, 0, stream>>>(
        Xh, WT, a_self, a_neigh, Vt, e_self, e_neigh, u_tab, v_tab);
    enmax_kernel<<<1, 512, 0, stream>>>(e_neigh, enmax);
    attn_kernel<<<(NODES / BM) * JSPLIT, 1024, 0, stream>>>(
        A, Vt, e_self, u_tab, v_tab, enmax, out_acc, psum);
    finalize_kernel<<<NODES * 512 / 4 / 256, 256, 0, stream>>>(out_acc, psum, b, out);
}